// Round 15
// baseline (113.607 us; speedup 1.0000x reference)
//
#include <hip/hip_runtime.h>
#include <math.h>

#define N_INW     1024
#define N_DEPTH   8
#define N_GROW    512
#define N_BATCH   4096
#define N_THREADS 128    // 2 independent waves/WG; wave cp owns ONE column
#define N_LAYERS  64
#define SLAB_B    9216   // 4608 rows * 2 B (fp16, 1 col) per wave -> 16 waves/CU

typedef __attribute__((ext_vector_type(2))) _Float16 h2;

// ---- setup: fp16 cs table + precomputed LDS byte-offsets (row*2) ----
// layer g, lane blk: 8 cos halves at byte g*2048 + blk*32, 8 sin halves at +16.
__global__ void precompute_kernel(const float* __restrict__ angles,
                                  const int*   __restrict__ indices,
                                  _Float16* __restrict__ csh,
                                  int*   __restrict__ addrs) {
    int i = blockIdx.x * blockDim.x + threadIdx.x;
    if (i < N_LAYERS * 512) {
        int g = i >> 9, p = i & 511, blk = p >> 3, j = p & 7;
        float a = angles[i];
        _Float16* base = csh + g * 1024 + blk * 16;
        base[j]     = (_Float16)cosf(a);
        base[8 + j] = (_Float16)sinf(a);
    }
    if (i < N_DEPTH * N_INW) addrs[i] = indices[i] << 1;   // byte offset = row*2
}

#define H(U)   __builtin_bit_cast(h2, (unsigned)(U))
#define PKU(x, y) __builtin_bit_cast(unsigned, __builtin_amdgcn_cvt_pkrtz((x), (y)))
#define BCL(U) ({ h2 _t = H(U); h2 _r; _r.x = _t.x; _r.y = _t.x; _r; })
#define BCH(U) ({ h2 _t = H(U); h2 _r; _r.x = _t.y; _r.y = _t.y; _r; })
#define BCLN(U) H(__builtin_bit_cast(unsigned, BCL(U)) ^ 0x80000000u)
#define BCHN(U) H(__builtin_bit_cast(unsigned, BCH(U)) ^ 0x80000000u)

// State: y0..y7 = value pairs (x0,x1)(x2,x3)...(x14,x15) of this wave's column.
// Stride-1 rotates WITHIN a register: y' = (c,c).y + (s,-s).swap(y).
#define R1(Y, CC, SN) do { unsigned _u = __builtin_bit_cast(unsigned, Y);      \
    h2 _sw = H((_u << 16) | (_u >> 16));                                       \
    Y = (CC) * (Y) + (SN) * _sw; } while (0)
#define RS1(C, S) do {                                                         \
    R1(y0, BCL(C.x), BCLN(S.x)); R1(y1, BCH(C.x), BCHN(S.x));                  \
    R1(y2, BCL(C.y), BCLN(S.y)); R1(y3, BCH(C.y), BCHN(S.y));                  \
    R1(y4, BCL(C.z), BCLN(S.z)); R1(y5, BCH(C.z), BCHN(S.z));                  \
    R1(y6, BCL(C.w), BCLN(S.w)); R1(y7, BCH(C.w), BCHN(S.w)); } while (0)
// Strides 2/4/8: element-wise on register pairs; packed consts come DIRECTLY
// from table words (la mapping verified: S2 pairs (y0,y1)=(la0,la1)=C.x ...).
#define RP(YA, YB, CH, SH) do { h2 _a = YA, _b = YB, _c = CH, _s = SH;         \
    YA = _c * _a + _s * _b; YB = _c * _b - _s * _a; } while (0)
#define RS2(C, S) do { RP(y0,y1,H(C.x),H(S.x)); RP(y2,y3,H(C.y),H(S.y));       \
    RP(y4,y5,H(C.z),H(S.z)); RP(y6,y7,H(C.w),H(S.w)); } while (0)
#define RS4(C, S) do { RP(y0,y2,H(C.x),H(S.x)); RP(y1,y3,H(C.y),H(S.y));       \
    RP(y4,y6,H(C.z),H(S.z)); RP(y5,y7,H(C.w),H(S.w)); } while (0)
#define RS8(C, S) do { RP(y0,y4,H(C.x),H(S.x)); RP(y1,y5,H(C.y),H(S.y));       \
    RP(y2,y6,H(C.z),H(S.z)); RP(y3,y7,H(C.w),H(S.w)); } while (0)

// cs layer G of current module into (CK,SK); csl already has lane offset.
#define LDCS(CK, SK, G) do { if (USE_TABLE) {                                  \
    const char* _b = csl + (G) * 2048;                                         \
    CK = *(const uint4*)(_b); SK = *(const uint4*)(_b + 16);                   \
  } else {                                                                     \
    const float4* _p = (const float4*)(anl + (G) * 512);                       \
    float4 _u = _p[0], _v = _p[1];                                             \
    float _c0,_c1,_c2,_c3,_c4,_c5,_c6,_c7,_t0,_t1,_t2,_t3,_t4,_t5,_t6,_t7;     \
    __sincosf(_u.x,&_t0,&_c0); __sincosf(_u.y,&_t1,&_c1);                      \
    __sincosf(_u.z,&_t2,&_c2); __sincosf(_u.w,&_t3,&_c3);                      \
    __sincosf(_v.x,&_t4,&_c4); __sincosf(_v.y,&_t5,&_c5);                      \
    __sincosf(_v.z,&_t6,&_c6); __sincosf(_v.w,&_t7,&_c7);                      \
    CK = make_uint4(PKU(_c0,_c1),PKU(_c2,_c3),PKU(_c4,_c5),PKU(_c6,_c7));      \
    SK = make_uint4(PKU(_t0,_t1),PKU(_t2,_t3),PKU(_t4,_t5),PKU(_t6,_t7));      \
  } } while (0)

#define LDADDR() do { if (USE_TABLE) {                                         \
    const int4* _ip = (const int4*)(atl);                                      \
    i0 = _ip[0]; i1 = _ip[1]; i2 = _ip[2]; i3 = _ip[3];                        \
  } else {                                                                     \
    const int4* _ip = (const int4*)(inl);                                      \
    int4 _a = _ip[0], _b = _ip[1], _c = _ip[2], _d = _ip[3];                   \
    i0.x=_a.x<<1; i0.y=_a.y<<1; i0.z=_a.z<<1; i0.w=_a.w<<1;                    \
    i1.x=_b.x<<1; i1.y=_b.y<<1; i1.z=_b.z<<1; i1.w=_b.w<<1;                    \
    i2.x=_c.x<<1; i2.y=_c.y<<1; i2.z=_c.z<<1; i2.w=_c.w<<1;                    \
    i3.x=_d.x<<1; i3.y=_d.y<<1; i3.z=_d.z<<1; i3.w=_d.w<<1;                    \
  } } while (0)

#define LDBIAS() do { const float4* _bp = (const float4*)(bil);                \
    float4 _a = _bp[0], _b = _bp[1];                                           \
    bb0 = H(PKU(_a.x,_a.y)); bb1 = H(PKU(_a.z,_a.w));                          \
    bb2 = H(PKU(_b.x,_b.y)); bb3 = H(PKU(_b.z,_b.w)); } while (0)

#define GPAIR(Y, A0, A1) do {                                                  \
    unsigned _lo = *(const unsigned short*)(L + (A0));                         \
    unsigned _hi = *(const unsigned short*)(L + (A1));                         \
    Y = H(_lo | (_hi << 16)); } while (0)
#define SPAIR(Y, A0, A1) do { unsigned _w = __builtin_bit_cast(unsigned, Y);   \
    *(unsigned short*)(L + (A0)) = (unsigned short)_w;                         \
    *(unsigned short*)(L + (A1)) = (unsigned short)(_w >> 16); } while (0)
#define GATHER() do {                                                          \
    GPAIR(y0, i0.x, i0.y); GPAIR(y1, i0.z, i0.w);                              \
    GPAIR(y2, i1.x, i1.y); GPAIR(y3, i1.z, i1.w);                              \
    GPAIR(y4, i2.x, i2.y); GPAIR(y5, i2.z, i2.w);                              \
    GPAIR(y6, i3.x, i3.y); GPAIR(y7, i3.z, i3.w); } while (0)
#define SCATTER() do {                                                         \
    SPAIR(y0, i0.x, i0.y); SPAIR(y1, i0.z, i0.w);                              \
    SPAIR(y2, i1.x, i1.y); SPAIR(y3, i1.z, i1.w);                              \
    SPAIR(y4, i2.x, i2.y); SPAIR(y5, i2.z, i2.w);                              \
    SPAIR(y6, i3.x, i3.y); SPAIR(y7, i3.z, i3.w); } while (0)

#define ACT(Y, BB) do {                                                        \
    float _lo = (float)(Y).x + (float)(BB).x;                                  \
    float _hi = (float)(Y).y + (float)(BB).y;                                  \
    _lo = 0.5f * (_lo + __builtin_amdgcn_sqrtf(_lo * _lo + 1.0f));             \
    _hi = 0.5f * (_hi + __builtin_amdgcn_sqrtf(_hi * _hi + 1.0f));             \
    Y = H(PKU(_lo, _hi)); } while (0)

#define FENCE() __builtin_amdgcn_sched_barrier(0)

// Barrier-free (each wave owns a private 1-col slab; in-order DS pipe covers
// intra-wave RAW). cs IN-set prefetched a half-module ahead behind fences
// (r10: proven necessary); addr/bias JIT at module top (covered by 4 w/SIMD).
template <bool USE_TABLE>
__global__ __launch_bounds__(N_THREADS, 4)   // 16 waves/CU, VGPR cap 128
void butterfly_fused_kernel(const float* __restrict__ input,
                            const float* __restrict__ scales,
                            const float* __restrict__ biases,
                            const int*   __restrict__ indices,
                            const char*  __restrict__ cs_tab,
                            const int*   __restrict__ addr_tab,
                            const float* __restrict__ angles,
                            float* __restrict__ out) {
    extern __shared__ char ldsbuf[];
    const int t   = threadIdx.x;
    const int blk = t & 63;                    // butterfly block = lane
    const int cp  = t >> 6;                    // wave id (independent column)
    char* L = ldsbuf + cp * SLAB_B;            // private per-wave slab
    const int b   = blockIdx.x;
    // XCD swizzle: blockIdx%8 == x owns columns [x*512,(x+1)*512)
    const int cg  = (((b & 7) * 256) + (b >> 3)) * 2 + cp;

    // running lane-adjusted bases
    const char*  csl = cs_tab + (blk << 5);
    const float* anl = angles + (blk << 3);
    const int*   atl = addr_tab + (blk << 4);
    const int*   inl = indices + (blk << 4);
    const float* bil = biases + (blk << 3);

    uint4 cI0,sI0,cI1,sI1,cI2,sI2,cI3,sI3;     // IN cs (prefetched)
    uint4 cO0,sO0,cO1,sO1,cO2,sO2,cO3,sO3;     // OUT cs
    int4  i0, i1, i2, i3;                      // gather/scatter byte addrs
    h2    bb0, bb1, bb2, bb3;                  // bias pairs
    h2    y0, y1, y2, y3, y4, y5, y6, y7;      // state: 16 values of 1 col

    // prologue: module 0 IN cs
    LDCS(cI0,sI0,0); LDCS(cI1,sI1,1); LDCS(cI2,sI2,2); LDCS(cI3,sI3,3);

    // init: rows 0..1023 = scales[r] * input[r][cg]  (fp16 store)
#pragma unroll
    for (int k = 0; k < 16; ++k) {
        const int r = (k << 6) + blk;
        float v = scales[r] * input[(size_t)r * N_BATCH + cg];
        *(unsigned short*)(L + (r << 1)) =
            __builtin_bit_cast(unsigned short, (_Float16)v);
    }

#pragma unroll 1
    for (int m = 0; m < 7; ++m) {
        LDADDR(); LDBIAS();
        GATHER();
        LDCS(cO0,sO0,4); LDCS(cO1,sO1,5); LDCS(cO2,sO2,6); LDCS(cO3,sO3,7);
        FENCE();
        // consume IN cs (prefetched during previous module)
        RS1(cI0,sI0); RS2(cI1,sI1); RS4(cI2,sI2); RS8(cI3,sI3);
        ACT(y0,bb0); ACT(y1,bb1); ACT(y2,bb2); ACT(y3,bb3);
        // append act rows (16 contiguous bytes, 16-aligned)
        { unsigned* ap = (unsigned*)(L + 2048 + m * 1024 + (blk << 4));
          ap[0] = __builtin_bit_cast(unsigned, y0);
          ap[1] = __builtin_bit_cast(unsigned, y1);
          ap[2] = __builtin_bit_cast(unsigned, y2);
          ap[3] = __builtin_bit_cast(unsigned, y3); }
        // prefetch next module's IN cs (consumed after next gather)
        LDCS(cI0,sI0,8); LDCS(cI1,sI1,9); LDCS(cI2,sI2,10); LDCS(cI3,sI3,11);
        FENCE();
        RS1(cO0,sO0); RS2(cO1,sO1); RS4(cO2,sO2); RS8(cO3,sO3);
        SCATTER();
        csl += 16384; anl += 4096; atl += N_INW; inl += N_INW; bil += N_GROW;
    }

    // epilogue: module 7 — OUT rotations + scatter are dead code w.r.t. the
    // output; output = module-7 activations (fp16 -> fp32).
    {
        LDADDR(); LDBIAS();
        GATHER();
        FENCE();
        RS1(cI0,sI0); RS2(cI1,sI1); RS4(cI2,sI2); RS8(cI3,sI3);
        ACT(y0,bb0); ACT(y1,bb1); ACT(y2,bb2); ACT(y3,bb3);
        out[(size_t)((blk<<3)+0)*N_BATCH + cg] = (float)y0.x;
        out[(size_t)((blk<<3)+1)*N_BATCH + cg] = (float)y0.y;
        out[(size_t)((blk<<3)+2)*N_BATCH + cg] = (float)y1.x;
        out[(size_t)((blk<<3)+3)*N_BATCH + cg] = (float)y1.y;
        out[(size_t)((blk<<3)+4)*N_BATCH + cg] = (float)y2.x;
        out[(size_t)((blk<<3)+5)*N_BATCH + cg] = (float)y2.y;
        out[(size_t)((blk<<3)+6)*N_BATCH + cg] = (float)y3.x;
        out[(size_t)((blk<<3)+7)*N_BATCH + cg] = (float)y3.y;
    }
}

// ---------------- host ----------------
extern "C" void kernel_launch(void* const* d_in, const int* in_sizes, int n_in,
                              void* d_out, int out_size, void* d_ws, size_t ws_size,
                              hipStream_t stream) {
    const float* input   = (const float*)d_in[0];
    const float* scales  = (const float*)d_in[1];
    const float* angles  = (const float*)d_in[2];
    const float* biases  = (const float*)d_in[3];
    const int*   indices = (const int*)d_in[4];
    float* out = (float*)d_out;

    const size_t cs_bytes  = (size_t)N_LAYERS * 2048;                    // 128 KB fp16
    const size_t adr_bytes = (size_t)N_DEPTH * N_INW * sizeof(int);      // 32 KB
    const size_t lds_bytes = (size_t)2 * SLAB_B;                         // 18432 B
    const int grid = N_BATCH / 2;                                        // 2048 WGs

    if (ws_size >= cs_bytes + adr_bytes) {
        _Float16* csh = (_Float16*)d_ws;
        int* addrs = (int*)((char*)d_ws + cs_bytes);
        precompute_kernel<<<(N_LAYERS * 512 + 255) / 256, 256, 0, stream>>>(
            angles, indices, csh, addrs);
        butterfly_fused_kernel<true><<<grid, N_THREADS, lds_bytes, stream>>>(
            input, scales, biases, indices, (const char*)csh, addrs, angles, out);
    } else {
        butterfly_fused_kernel<false><<<grid, N_THREADS, lds_bytes, stream>>>(
            input, scales, biases, indices, nullptr, nullptr, angles, out);
    }
}